// Round 3
// baseline (1369.002 us; speedup 1.0000x reference)
//
#include <hip/hip_runtime.h>
#include <hip/hip_bf16.h>
#include <math.h>

#define EMBED_DIM 512
#define NUM_CLASSES 100000
#define NUM_SUB 3
#define BATCH 256
#define M_TOTAL (NUM_CLASSES*NUM_SUB)   // 300000
#define BM 48                            // weight rows per block = 16 whole classes
#define NBLOCKS (M_TOTAL/BM)             // 6250

typedef float  floatx4 __attribute__((ext_vector_type(4)));
typedef __bf16 bf16x8  __attribute__((ext_vector_type(8)));

// round-to-nearest-even fp32 -> bf16 (bit trick)
__device__ __forceinline__ unsigned int f2bf(float f){
  unsigned int u = __float_as_uint(f);
  u += 0x7FFFu + ((u >> 16) & 1u);
  return u >> 16;
}

// ---------------- kernel 1: normalize embeddings, pack bf16, K-tile-major ----
// ehat layout: [kt=K/64][batch=256][64] bf16 (262 KB -> L2/L3-resident); the
// GEMM kernel gathers A fragments straight from it.
__global__ __launch_bounds__(64) void normalize_pack(
    const float* __restrict__ E, unsigned short* __restrict__ ehat)
{
  const int r    = blockIdx.x;     // batch row
  const int lane = threadIdx.x;    // 64 lanes, 8 floats each
  const float4 v0 = *(const float4*)(E + r*EMBED_DIM + lane*8);
  const float4 v1 = *(const float4*)(E + r*EMBED_DIM + lane*8 + 4);
  float ssq = v0.x*v0.x + v0.y*v0.y + v0.z*v0.z + v0.w*v0.w
            + v1.x*v1.x + v1.y*v1.y + v1.z*v1.z + v1.w*v1.w;
  #pragma unroll
  for (int m = 1; m < 64; m <<= 1) ssq += __shfl_xor(ssq, m, 64);
  float nn = sqrtf(ssq);
  nn = fmaxf(nn, 1e-12f);           // matches F.normalize eps semantics
  const float rn = 1.0f / nn;
  const float vals[8] = {v0.x, v0.y, v0.z, v0.w, v1.x, v1.y, v1.z, v1.w};
  unsigned int p[4];
  #pragma unroll
  for (int i = 0; i < 4; ++i)
    p[i] = f2bf(vals[2*i]*rn) | (f2bf(vals[2*i+1]*rn) << 16);
  const int kt = lane >> 3;                       // (lane*8)/64
  const size_t off = (size_t)kt*(BATCH*64) + (size_t)r*64 + (lane & 7)*8;
  *(uint4*)(ehat + off) = make_uint4(p[0], p[1], p[2], p[3]);
}

// ---------------- kernel 2: fused GEMM + norm + subcenter-max + margin + exp --
// BARRIER-FREE main loop: no LDS staging at all. Each lane loads its MFMA
// B-fragment (8 consecutive fp32) directly from W (4 waves dup -> L2 hits),
// double-buffered 1 K-step ahead in fp32 registers; bf16 convert + row-ssq
// happen at consume time. A fragments come register-direct from L2-resident
// ehat. All waits are per-wave vmcnt -> loads stay in flight across MFMAs.
__global__ __launch_bounds__(256, 2) void arcface_main(
    const float* __restrict__ W,            // [300000][512] fp32 row-major
    const unsigned short* __restrict__ ehat,// blocked bf16 (see above)
    const int* __restrict__ labels,
    float* __restrict__ gsum,               // [256] stride-16 fp32 accumulators
    float* __restrict__ llogit)             // [256] fp32, 64*phi at label class
{
  __shared__ float ebuf_all[4*16*49];       // epilogue only, 12544 B

  const int tid  = threadIdx.x;
  const int wave = tid >> 6, lane = tid & 63;
  const int col  = lane & 15, quad = lane >> 4;
  const int m0   = blockIdx.x * BM;

  floatx4 acc[12] = {};                 // 4 row-tiles(batch) x 3 col-tiles(weight)
  float   ssq[3]  = {0,0,0};

  // A fragment base: row = wave*64 + rt*16 + col, k = kt*64 + h*32 + quad*8
  const unsigned short* abase = ehat + (wave*64 + col)*64 + quad*8;
  // this lane's 3 B-fragment rows (n = ct*16 + col), k base = quad*8
  const float* wrow[3];
  #pragma unroll
  for (int ct = 0; ct < 3; ++ct)
    wrow[ct] = W + (size_t)(m0 + ct*16 + col)*EMBED_DIM + quad*8;

  float4 fvA[3][2][2], fvB[3][2][2];    // fp32 W staging, double-buffered
  bf16x8 a[4][2], b[3][2];

#define LOADW(dst, ktv) do {                                              \
    _Pragma("unroll")                                                     \
    for (int ct = 0; ct < 3; ++ct){                                       \
      const float* wp = wrow[ct] + (ktv)*64;                              \
      _Pragma("unroll")                                                   \
      for (int h = 0; h < 2; ++h){                                        \
        dst[ct][h][0] = *(const float4*)(wp + h*32);                      \
        dst[ct][h][1] = *(const float4*)(wp + h*32 + 4);                  \
      }                                                                   \
    }                                                                     \
  } while(0)

#define CONVB(src) do {                                                   \
    _Pragma("unroll")                                                     \
    for (int ct = 0; ct < 3; ++ct){                                       \
      _Pragma("unroll")                                                   \
      for (int h = 0; h < 2; ++h){                                        \
        const float4 v0 = src[ct][h][0], v1 = src[ct][h][1];              \
        ssq[ct] += v0.x*v0.x + v0.y*v0.y + v0.z*v0.z + v0.w*v0.w          \
                 + v1.x*v1.x + v1.y*v1.y + v1.z*v1.z + v1.w*v1.w;         \
        union { uint4 u; bf16x8 h8; } cv;                                 \
        cv.u = make_uint4(f2bf(v0.x) | (f2bf(v0.y) << 16),                \
                          f2bf(v0.z) | (f2bf(v0.w) << 16),                \
                          f2bf(v1.x) | (f2bf(v1.y) << 16),                \
                          f2bf(v1.z) | (f2bf(v1.w) << 16));               \
        b[ct][h] = cv.h8;                                                 \
      }                                                                   \
    }                                                                     \
  } while(0)

#define LOADA(ktv) do {                                                   \
    _Pragma("unroll")                                                     \
    for (int rt = 0; rt < 4; ++rt)                                        \
      _Pragma("unroll")                                                   \
      for (int h = 0; h < 2; ++h)                                         \
        a[rt][h] = *(const bf16x8*)(abase + (ktv)*16384 + rt*1024 + h*32);\
  } while(0)

#define MFMAS() do {                                                      \
    _Pragma("unroll")                                                     \
    for (int h = 0; h < 2; ++h)                                           \
      _Pragma("unroll")                                                   \
      for (int rt = 0; rt < 4; ++rt)                                      \
        _Pragma("unroll")                                                 \
        for (int ct = 0; ct < 3; ++ct)                                    \
          acc[rt*3 + ct] = __builtin_amdgcn_mfma_f32_16x16x32_bf16(       \
              a[rt][h], b[ct][h], acc[rt*3 + ct], 0, 0, 0);               \
  } while(0)

  // prologue: two K-steps of W in flight
  LOADW(fvA, 0);
  LOADW(fvB, 1);

  #pragma unroll 1
  for (int kt = 0; kt < 8; kt += 2){
    LOADA(kt);                       // L2 gathers, covered by CONVB below
    CONVB(fvA);                      // waits on W[kt] (issued ~1 iter ago)
    if (kt + 2 < 8) LOADW(fvA, kt + 2);
    MFMAS();                         // kt
    LOADA(kt + 1);
    CONVB(fvB);                      // waits on W[kt+1] (full-iter distance)
    if (kt + 3 < 8) LOADW(fvB, kt + 3);
    MFMAS();                         // kt+1
  }
#undef LOADW
#undef CONVB
#undef LOADA
#undef MFMAS

  // ---- weight-row norms fully in-register: reduce ssq over the 4 quads -----
  float rnorm3[3];
  #pragma unroll
  for (int ct = 0; ct < 3; ++ct){
    float s = ssq[ct];
    s += __shfl_xor(s, 16, 64);
    s += __shfl_xor(s, 32, 64);
    rnorm3[ct] = 1.0f / fmaxf(sqrtf(s), 1e-12f);   // row ct*16+col
  }

  // ---- epilogue: cosine -> LDS -> subcenter max -> margin -> exp-sum -------
  float* ebuf = ebuf_all + wave*(16*49);   // per-wave private 3.1 KB slice
  const int cls0 = m0 / 3;
  const float cos_m = 0.87758256189037276f;
  const float sin_m = 0.47942553860420301f;
  const float thr   = -0.87758256189037276f;   // cos(pi - m)
  const float mmv   = 0.23971276930210156f;    // sin(pi - m)*m

  #pragma unroll
  for (int rt = 0; rt < 4; ++rt){
    // write this chunk's 16 x 48 cosines (stride 49)
    #pragma unroll
    for (int ct = 0; ct < 3; ++ct)
      #pragma unroll
      for (int r = 0; r < 4; ++r)
        ebuf[(quad*4 + r)*49 + ct*16 + col] = acc[rt*3 + ct][r] * rnorm3[ct];
    __syncthreads();
    // read phase: lanes 0..15 each own one batch row of this chunk
    if (quad == 0){
      const int brow = wave*64 + rt*16 + col;
      const int lbl  = labels[brow];
      float contrib = 0.0f;
      for (int c = 0; c < 16; ++c){
        const float a0 = ebuf[col*49 + 3*c + 0];
        const float a1 = ebuf[col*49 + 3*c + 1];
        const float a2 = ebuf[col*49 + 3*c + 2];
        float cm = fmaxf(a0, fmaxf(a1, a2));
        float val = cm;
        if (cls0 + c == lbl){
          const float sine = sqrtf(fmaxf(0.0f, 1.0f - cm*cm));
          const float phi  = cm*cos_m - sine*sin_m;
          val = (cm > thr) ? phi : (cm - mmv);
          llogit[brow] = 64.0f * val;
        }
        contrib += __expf(64.0f*val - 64.0f);   // logits <= 64 always -> safe shift
      }
      atomicAdd(&gsum[brow*16], contrib);
    }
    __syncthreads();
  }
}

// ---------------- kernel 3: loss = mean(log(sum) + 64 - label_logit) --------
__global__ __launch_bounds__(256) void finalize_loss(
    const float* __restrict__ gsum, const float* __restrict__ llogit,
    float* __restrict__ out)
{
  const int tid = threadIdx.x;
  float v = logf(gsum[tid*16]) + 64.0f - llogit[tid];
  #pragma unroll
  for (int m = 1; m < 64; m <<= 1) v += __shfl_xor(v, m, 64);
  __shared__ float red[4];
  if ((tid & 63) == 0) red[tid >> 6] = v;
  __syncthreads();
  if (tid == 0) out[0] = (red[0] + red[1] + red[2] + red[3]) * (1.0f/BATCH);
}

extern "C" void kernel_launch(void* const* d_in, const int* in_sizes, int n_in,
                              void* d_out, int out_size, void* d_ws, size_t ws_size,
                              hipStream_t stream)
{
  const float* emb    = (const float*)d_in[0];
  const int*   labels = (const int*)d_in[1];
  const float* W      = (const float*)d_in[2];

  // workspace layout: ehat bf16 blocked (262144 B) | gsum (16384 B) | llogit (1024 B)
  unsigned short* ehat   = (unsigned short*)d_ws;
  float*          gsum   = (float*)((char*)d_ws + 262144);
  float*          llogit = (float*)((char*)d_ws + 262144 + 16384);

  hipMemsetAsync(gsum, 0, 16384, stream);
  normalize_pack<<<BATCH, 64, 0, stream>>>(emb, ehat);
  arcface_main<<<NBLOCKS, 256, 0, stream>>>(W, ehat, labels, gsum, llogit);
  finalize_loss<<<1, 256, 0, stream>>>(gsum, llogit, (float*)d_out);
}